// Round 5
// baseline (688.748 us; speedup 1.0000x reference)
//
#include <hip/hip_runtime.h>

// Problem constants (match the reference)
constexpr int T    = 4096;
constexpr int N    = 16;
constexpr int C    = 512;
constexpr int NC   = N * C;       // 8192 columns
constexpr int NC4  = NC / 4;      // 2048 float4 columns
constexpr int TNC  = T * NC;

// Single-pass decoupled-lookback scan geometry
constexpr int RB   = 64;          // rows per block (one chunk)
constexpr int CB   = 64;          // float4-cols per block (one strip)
constexpr int RT   = 16;          // rows per thread (16 float4 = 64 VGPR, static idx)
constexpr int NCH  = T / RB;      // 64 chunks
constexpr int NST  = NC4 / CB;    // 32 strips
constexpr int NBLK = NCH * NST;   // 2048 blocks

__device__ __forceinline__ void acc(float4& a, const float4& b) {
    a.x += b.x; a.y += b.y; a.z += b.z; a.w += b.w;
}

// ---------------------------------------------------------------------------
// ONE pass over x: each block = (chunk ch, strip). 256 thr: rg = tid>>6 (4 row
// groups), col = tid&63. Thread holds its 16 rows in registers (single HBM
// read), block aggregate published immediately (release, agent scope — per-XCD
// L2s are not coherent), CUB-style lookback with SEPARATE agg/incl slots (no
// flag/value overwrite race), then finalize from registers (single HBM write).
// blockIdx is ch-major so predecessor chunks dispatch first (forward-progress
// assumption, same as CUB/hipCUB decoupled lookback).
// ---------------------------------------------------------------------------
__global__ __launch_bounds__(256) void pool_scan(
    const float* __restrict__ x,
    const int*   __restrict__ cached_len,
    const float* __restrict__ cached_avg,
    float*       __restrict__ out,
    float*       __restrict__ out_len,
    float*       __restrict__ out_avg,
    int*         __restrict__ flag_agg,   // [NBLK], zeroed per launch
    int*         __restrict__ flag_incl,  // [NBLK], zeroed per launch
    float4*      __restrict__ vagg,       // [NBLK][CB]
    float4*      __restrict__ vincl)      // [NBLK][CB]
{
    const int bid   = blockIdx.x;
    const int ch    = bid >> 5;           // / NST
    const int strip = bid & (NST - 1);
    const int rg    = threadIdx.x >> 6;   // row group 0..3
    const int col   = threadIdx.x & 63;   // f4-col within strip (= lane)
    const int col4  = strip * CB + col;
    const int row0  = ch * RB + rg * RT;
    const int nIdx  = col4 >> 7;          // uniform per block (CB=64 never crosses)
    const float lenf = (float)cached_len[nIdx];

    __shared__ float4 xch[4][CB];         // row-group partial sums (4 KB)
    __shared__ float4 exch[CB];           // chunk-exclusive broadcast (1 KB)

    // Phase A: load 16 rows into registers (fully static indices -> VGPRs),
    // coalesced: a wave's 64 lanes cover 1 KB contiguous per row.
    const float4* xp = reinterpret_cast<const float4*>(x);
    float4 v[RT];
    float4 sum = make_float4(0.f, 0.f, 0.f, 0.f);
#pragma unroll
    for (int i = 0; i < RT; ++i) {
        v[i] = xp[(row0 + i) * NC4 + col4];
        acc(sum, v[i]);
    }

    // Phase B: row-group exclusive prefix within the block via LDS.
    xch[rg][col] = sum;
    __syncthreads();
    float4 rgpre = make_float4(0.f, 0.f, 0.f, 0.f);
#pragma unroll
    for (int r = 0; r < 3; ++r)
        if (r < rg) acc(rgpre, xch[r][col]);

    // Phase C (wave 0 only): publish aggregate, lookback, publish inclusive.
    if (rg == 0) {
        float4 tot = xch[0][col];
        acc(tot, xch[1][col]); acc(tot, xch[2][col]); acc(tot, xch[3][col]);
        vagg[bid * CB + col] = tot;
        __threadfence();      // wave-level: drains the wave's value stores
        if (threadIdx.x == 0)
            __hip_atomic_store(&flag_agg[bid], 1, __ATOMIC_RELEASE,
                               __HIP_MEMORY_SCOPE_AGENT);

        float4 excl = make_float4(0.f, 0.f, 0.f, 0.f);
        int walk = ch - 1;
        int spin = 0;
        while (walk >= 0) {
            const int sidx = walk * NST + strip;
            if (__hip_atomic_load(&flag_incl[sidx], __ATOMIC_ACQUIRE,
                                  __HIP_MEMORY_SCOPE_AGENT)) {
                acc(excl, vincl[sidx * CB + col]);
                break;
            }
            if (__hip_atomic_load(&flag_agg[sidx], __ATOMIC_ACQUIRE,
                                  __HIP_MEMORY_SCOPE_AGENT)) {
                acc(excl, vagg[sidx * CB + col]);
                --walk;
                continue;
            }
            __builtin_amdgcn_s_sleep(8);
            if (++spin > (1 << 22)) break;   // bounded: fail check, don't wedge GPU
        }

        float4 incl = excl;
        acc(incl, tot);
        vincl[bid * CB + col] = incl;
        __threadfence();
        if (threadIdx.x == 0)
            __hip_atomic_store(&flag_incl[bid], 1, __ATOMIC_RELEASE,
                               __HIP_MEMORY_SCOPE_AGENT);
        exch[col] = excl;
    }
    __syncthreads();

    // Phase D: finalize from registers. s = chunk-exclusive + rg-prefix,
    // then running-sum rows, add cached base last, exact divide, store.
    float4 s = exch[col];
    acc(s, rgpre);
    float4 b = reinterpret_cast<const float4*>(cached_avg)[col4];
    b.x *= lenf; b.y *= lenf; b.z *= lenf; b.w *= lenf;

    float4* op = reinterpret_cast<float4*>(out);
    float4 o = make_float4(0.f, 0.f, 0.f, 0.f);
#pragma unroll
    for (int i = 0; i < RT; ++i) {
        acc(s, v[i]);
        const int t = row0 + i;
        const float r = 1.0f / ((float)(t + 1) + lenf);   // match ref rounding
        o.x = (s.x + b.x) * r;
        o.y = (s.y + b.y) * r;
        o.z = (s.z + b.z) * r;
        o.w = (s.w + b.w) * r;
        op[t * NC4 + col4] = o;
    }

    if (ch == NCH - 1 && rg == 3)
        reinterpret_cast<float4*>(out_avg)[col4] = o;     // new_x[-1]
    if (bid == 0 && threadIdx.x < N)
        out_len[threadIdx.x] = (float)(cached_len[threadIdx.x] + T);
        // NOTE: harness reads whole d_out as float32 -> store int output as values
}

// ---------------------------------------------------------------------------
extern "C" void kernel_launch(void* const* d_in, const int* in_sizes, int n_in,
                              void* d_out, int out_size, void* d_ws, size_t ws_size,
                              hipStream_t stream)
{
    const float* x          = (const float*)d_in[0];
    const int*   cached_len = (const int*)d_in[1];
    const float* cached_avg = (const float*)d_in[2];

    // d_out (ALL float32): new_x | new_cached_len (as float values) | new_cached_avg
    float* out     = (float*)d_out;
    float* out_len = out + TNC;
    float* out_avg = out + TNC + N;

    // Workspace: [flags_agg 8K][flags_incl 8K][vagg 2MB][vincl 2MB]
    char* ws = (char*)d_ws;
    int*    flag_agg  = (int*)ws;
    int*    flag_incl = (int*)(ws + 8192);
    float4* vagg      = (float4*)(ws + 16384);
    float4* vincl     = (float4*)(ws + 16384 + (size_t)NBLK * CB * 16);

    // Re-arm flags every launch (ws is poisoned 0xAA before each timed call).
    hipMemsetAsync(d_ws, 0, 16384, stream);

    pool_scan<<<NBLK, 256, 0, stream>>>(x, cached_len, cached_avg,
                                        out, out_len, out_avg,
                                        flag_agg, flag_incl, vagg, vincl);
}

// Round 8
// 443.659 us; speedup vs baseline: 1.5524x; 1.5524x over previous
//
#include <hip/hip_runtime.h>

// Problem constants (match the reference)
constexpr int T    = 4096;
constexpr int N    = 16;
constexpr int C    = 512;
constexpr int NC   = N * C;       // 8192 columns
constexpr int NC4  = NC / 4;      // 2048 float4 columns
constexpr int TNC  = T * NC;

// Single-pass scan geometry
constexpr int RB   = 64;          // rows per block (one chunk)
constexpr int CB   = 64;          // float4-cols per block (one strip)
constexpr int RT   = 16;          // rows per thread (16 float4 = 64 VGPR, static idx)
constexpr int NCH  = T / RB;      // 64 chunks  (<= 64 so one lane per predecessor)
constexpr int NST  = NC4 / CB;    // 32 strips
constexpr int NBLK = NCH * NST;   // 2048 blocks

using f4v = __attribute__((ext_vector_type(4))) float;

__device__ __forceinline__ void acc(float4& a, const float4& b) {
    a.x += b.x; a.y += b.y; a.z += b.z; a.w += b.w;
}

// ---------------------------------------------------------------------------
// ONE pass over x. Block = (chunk ch, strip). 256 thr = 4 row-groups x 64 cols.
// Thread holds its 16 rows in registers (launch_bounds(256,2) raises the VGPR
// cap to 256 so this does NOT spill — round-5 failure was a silent spill at
// VGPR cap 64). Chunk aggregate published immediately (release, agent scope;
// per-XCD L2s are not coherent). PARALLEL windowed lookback: wave0's lanes
// poll all <=63 predecessor agg-flags concurrently (ballot), then sum their
// aggregates with independent pipelined loads — no serial dependent chain,
// no incl flags at all. Finalize from registers, non-temporal stores (new_x
// is never re-read; keep the LLC for x + spine).
// Publish-before-wait guarantees no deadlock: a block's aggregate depends
// only on its own data, and blocks only wait on lower blockIdx (dispatched
// earlier — standard decoupled-lookback forward-progress assumption).
// ---------------------------------------------------------------------------
__global__ __launch_bounds__(256, 2) void pool_scan(
    const float* __restrict__ x,
    const int*   __restrict__ cached_len,
    const float* __restrict__ cached_avg,
    float*       __restrict__ out,
    float*       __restrict__ out_len,
    float*       __restrict__ out_avg,
    int*         __restrict__ flag_agg,   // [NBLK], zeroed per launch
    float4*      __restrict__ vagg)       // [NBLK][CB]
{
    const int bid   = blockIdx.x;
    const int ch    = bid >> 5;           // / NST  (ch-major: preds dispatch first)
    const int strip = bid & (NST - 1);
    const int rg    = threadIdx.x >> 6;   // row group 0..3
    const int col   = threadIdx.x & 63;   // f4-col within strip (= lane in wave)
    const int col4  = strip * CB + col;
    const int row0  = ch * RB + rg * RT;
    const int nIdx  = col4 >> 7;          // uniform per block (CB=64 never crosses n)
    const float lenf = (float)cached_len[nIdx];

    __shared__ float4 xch[4][CB];         // row-group sums (4 KB)
    __shared__ float4 exch[CB];           // chunk-exclusive broadcast (1 KB)

    // Phase A: 16 rows -> registers. Coalesced: wave covers 1 KB/row.
    const float4* xp = reinterpret_cast<const float4*>(x);
    float4 v[RT];
    float4 sum = make_float4(0.f, 0.f, 0.f, 0.f);
#pragma unroll
    for (int i = 0; i < RT; ++i) {
        v[i] = xp[(row0 + i) * NC4 + col4];
        acc(sum, v[i]);
    }

    // Phase B: row-group exclusive prefix within the block via LDS.
    xch[rg][col] = sum;
    __syncthreads();
    float4 rgpre = make_float4(0.f, 0.f, 0.f, 0.f);
#pragma unroll
    for (int r = 0; r < 3; ++r)
        if (r < rg) acc(rgpre, xch[r][col]);

    // Phase C (wave 0 only): publish aggregate, parallel lookback, broadcast.
    if (rg == 0) {
        float4 tot = xch[0][col];
        acc(tot, xch[1][col]); acc(tot, xch[2][col]); acc(tot, xch[3][col]);
        vagg[bid * CB + col] = tot;
        __threadfence();
        if (col == 0)
            __hip_atomic_store(&flag_agg[bid], 1, __ATOMIC_RELEASE,
                               __HIP_MEMORY_SCOPE_AGENT);

        // Wait until ALL predecessors (0..ch-1) published — one lane per pred.
        bool done = (col >= ch);
        int spin = 0;
        while (__ballot(!done)) {
            if (!done)
                done = __hip_atomic_load(&flag_agg[col * NST + strip],
                                         __ATOMIC_ACQUIRE,
                                         __HIP_MEMORY_SCOPE_AGENT) != 0;
            if (++spin > (1 << 24)) break;   // bounded: fail check, don't wedge
        }

        // Sum predecessor aggregates: independent loads, deep in flight.
        float4 excl = make_float4(0.f, 0.f, 0.f, 0.f);
#pragma unroll 4
        for (int j = 0; j < ch; ++j)
            acc(excl, vagg[(j * NST + strip) * CB + col]);
        exch[col] = excl;
    }
    __syncthreads();

    // Phase D: finalize from registers. s = chunk-exclusive + rg-prefix, then
    // running-sum rows, add cached base last, exact fp32 divide (ref rounding).
    float4 s = exch[col];
    acc(s, rgpre);
    float4 b = reinterpret_cast<const float4*>(cached_avg)[col4];
    b.x *= lenf; b.y *= lenf; b.z *= lenf; b.w *= lenf;

    float4* op = reinterpret_cast<float4*>(out);
    float4 o = make_float4(0.f, 0.f, 0.f, 0.f);
#pragma unroll
    for (int i = 0; i < RT; ++i) {
        acc(s, v[i]);
        const int t = row0 + i;
        const float r = 1.0f / ((float)(t + 1) + lenf);
        o.x = (s.x + b.x) * r;
        o.y = (s.y + b.y) * r;
        o.z = (s.z + b.z) * r;
        o.w = (s.w + b.w) * r;
        union { float4 s4; f4v v4; } u;
        u.s4 = o;
        __builtin_nontemporal_store(u.v4,
            reinterpret_cast<f4v*>(&op[t * NC4 + col4]));
    }

    if (ch == NCH - 1 && rg == 3)
        reinterpret_cast<float4*>(out_avg)[col4] = o;     // new_x[-1]
    if (bid == 0 && threadIdx.x < N)
        out_len[threadIdx.x] = (float)(cached_len[threadIdx.x] + T);
        // harness reads whole d_out as float32 -> int output stored as values
}

// ---------------------------------------------------------------------------
extern "C" void kernel_launch(void* const* d_in, const int* in_sizes, int n_in,
                              void* d_out, int out_size, void* d_ws, size_t ws_size,
                              hipStream_t stream)
{
    const float* x          = (const float*)d_in[0];
    const int*   cached_len = (const int*)d_in[1];
    const float* cached_avg = (const float*)d_in[2];

    // d_out (ALL float32): new_x | new_cached_len (as float values) | new_cached_avg
    float* out     = (float*)d_out;
    float* out_len = out + TNC;
    float* out_avg = out + TNC + N;

    // Workspace: [flag_agg 8K][vagg 2MB]
    char* ws = (char*)d_ws;
    int*    flag_agg = (int*)ws;
    float4* vagg     = (float4*)(ws + 8192);

    // Re-arm flags every launch (ws is poisoned 0xAA before each timed call).
    hipMemsetAsync(flag_agg, 0, NBLK * sizeof(int), stream);

    pool_scan<<<NBLK, 256, 0, stream>>>(x, cached_len, cached_avg,
                                        out, out_len, out_avg,
                                        flag_agg, vagg);
}